// Round 4
// baseline (567.281 us; speedup 1.0000x reference)
//
#include <hip/hip_runtime.h>
#include <hip/hip_bf16.h>
#include <stdint.h>

#define H       2048
#define LOGH    11
#define T_TOK   4096
#define NEXP    8
#define NATOM   64
#define NS      16384

typedef short bf16x8 __attribute__((ext_vector_type(8)));
typedef float f32x4  __attribute__((ext_vector_type(4)));

// native LDS float atomic add (fire-and-forget, no CAS loop, no result latency)
__device__ __forceinline__ void lds_add_f32(float* p, float v) {
  asm volatile("ds_add_f32 %0, %1"
               :
               : "v"((unsigned)(uintptr_t)p), "v"(v)
               : "memory");
}

// ---------------- convert x and W to bf16 (RNE) ----------------
__global__ __launch_bounds__(256) void cvt_kernel(
    const float* __restrict__ x, const float* __restrict__ W,
    unsigned short* __restrict__ xb, unsigned short* __restrict__ wb) {
  const int TH = T_TOK * H;
  const int WH = H * H;
  const int total4 = (TH + WH) / 4;
  for (int i = blockIdx.x * blockDim.x + threadIdx.x; i < total4;
       i += gridDim.x * blockDim.x) {
    int e0 = i * 4;
    const float* src;
    unsigned short* dst;
    if (e0 < TH) { src = x + e0; dst = xb + e0; }
    else         { src = W + (e0 - TH); dst = wb + (e0 - TH); }
    float4 v = *reinterpret_cast<const float4*>(src);
    ushort4 o;
    {
      union { float f; unsigned u; } c;
      c.f = v.x; c.u += 0x7fff + ((c.u >> 16) & 1); o.x = (unsigned short)(c.u >> 16);
      c.f = v.y; c.u += 0x7fff + ((c.u >> 16) & 1); o.y = (unsigned short)(c.u >> 16);
      c.f = v.z; c.u += 0x7fff + ((c.u >> 16) & 1); o.z = (unsigned short)(c.u >> 16);
      c.f = v.w; c.u += 0x7fff + ((c.u >> 16) & 1); o.w = (unsigned short)(c.u >> 16);
    }
    *reinterpret_cast<ushort4*>(dst) = o;
  }
}

// ---------------- weighted[e][s] = (softmax(eaw[e]) @ atoms)[s] * sigmoid(imp[e][s]) ----------------
__global__ __launch_bounds__(256) void weighted_kernel(
    const float* __restrict__ eaw, const float* __restrict__ atoms,
    const float* __restrict__ importance, float* __restrict__ weighted) {
  __shared__ float p[NATOM];
  const int e = blockIdx.x >> 3;
  const int chunk = blockIdx.x & 7;
  const int tid = threadIdx.x;
  if (tid < NATOM) p[tid] = eaw[e * NATOM + tid];
  __syncthreads();
  if (tid == 0) {
    float m = p[0];
    for (int a = 1; a < NATOM; ++a) m = fmaxf(m, p[a]);
    float s = 0.f;
    for (int a = 0; a < NATOM; ++a) { p[a] = expf(p[a] - m); s += p[a]; }
    float inv = 1.f / s;
    for (int a = 0; a < NATOM; ++a) p[a] *= inv;
  }
  __syncthreads();
  const int base = chunk * 2048 + tid;
  for (int it = 0; it < 8; ++it) {
    int s = base + it * 256;
    float acc = 0.f;
#pragma unroll 16
    for (int a = 0; a < NATOM; ++a) acc = fmaf(p[a], atoms[a * NS + s], acc);
    float imp = importance[e * NS + s];
    float sig = 1.f / (1.f + expf(-imp));
    weighted[e * NS + s] = acc * sig;
  }
}

// ---------------- bf16 MFMA GEMM: out[m][n] = sum_k xb[m][k] * wb[n][k] ----------------
__global__ __launch_bounds__(256) void gemm_kernel(
    const unsigned short* __restrict__ xb, const unsigned short* __restrict__ wb,
    float* __restrict__ out) {
  __shared__ __align__(16) unsigned short aLds[128 * 32];
  __shared__ __align__(16) unsigned short bLds[128 * 32];
  const int tid  = threadIdx.x;
  const int wave = tid >> 6;
  const int lane = tid & 63;
  const int m0 = blockIdx.y * 128;
  const int n0 = blockIdx.x * 128;
  const int wr = wave >> 1;
  const int wc = wave & 1;

  f32x4 acc[4][4];
#pragma unroll
  for (int i = 0; i < 4; ++i)
#pragma unroll
    for (int j = 0; j < 4; ++j)
#pragma unroll
      for (int r = 0; r < 4; ++r) acc[i][j][r] = 0.f;

  const int srow = lane >> 2;
  const int kcol = (lane & 3) * 8;

  for (int k0 = 0; k0 < H; k0 += 32) {
#pragma unroll
    for (int p = 0; p < 2; ++p) {
      const int g = p * 4 + wave;
      const unsigned short* ga = xb + (size_t)(m0 + g * 16 + srow) * H + k0 + kcol;
      const unsigned short* gb = wb + (size_t)(n0 + g * 16 + srow) * H + k0 + kcol;
      __builtin_amdgcn_global_load_lds(
          (const __attribute__((address_space(1))) unsigned int*)ga,
          (__attribute__((address_space(3))) unsigned int*)(aLds + g * 16 * 32), 16, 0, 0);
      __builtin_amdgcn_global_load_lds(
          (const __attribute__((address_space(1))) unsigned int*)gb,
          (__attribute__((address_space(3))) unsigned int*)(bLds + g * 16 * 32), 16, 0, 0);
    }
    __syncthreads();

    const int kc = (lane >> 4) * 8;
    const int ar = wr * 64 + (lane & 15);
    const int br = wc * 64 + (lane & 15);
    bf16x8 af[4], bfr[4];
#pragma unroll
    for (int i = 0; i < 4; ++i)
      af[i] = *reinterpret_cast<const bf16x8*>(aLds + (ar + i * 16) * 32 + kc);
#pragma unroll
    for (int j = 0; j < 4; ++j)
      bfr[j] = *reinterpret_cast<const bf16x8*>(bLds + (br + j * 16) * 32 + kc);
#pragma unroll
    for (int i = 0; i < 4; ++i)
#pragma unroll
      for (int j = 0; j < 4; ++j)
        acc[i][j] = __builtin_amdgcn_mfma_f32_16x16x32_bf16(af[i], bfr[j], acc[i][j], 0, 0, 0);
    __syncthreads();
  }

  const int cr = (lane >> 4) * 4;
  const int cc = lane & 15;
#pragma unroll
  for (int i = 0; i < 4; ++i)
#pragma unroll
    for (int j = 0; j < 4; ++j)
#pragma unroll
      for (int r = 0; r < 4; ++r)
        out[(size_t)(m0 + wr * 64 + i * 16 + cr + r) * H + (n0 + wc * 64 + j * 16 + cc)] =
            acc[i][j][r];
}

// ---------------- gate: one wave per token, exact fp32 top-2 ----------------
__global__ __launch_bounds__(256) void gate_kernel(
    const float* __restrict__ x, const float* __restrict__ gate_w,
    float4* __restrict__ tokInfo) {
  const int wv = threadIdx.x >> 6;
  const int lane = threadIdx.x & 63;
  const int t = blockIdx.x * 4 + wv;
  const float4* xr = reinterpret_cast<const float4*>(x + (size_t)t * H);

  float accs[NEXP];
#pragma unroll
  for (int e = 0; e < NEXP; ++e) accs[e] = 0.f;
#pragma unroll
  for (int it = 0; it < 8; ++it) {
    const int j4 = it * 64 + lane;
    float4 xv = xr[j4];
#pragma unroll
    for (int e = 0; e < NEXP; ++e) {
      float4 gv = reinterpret_cast<const float4*>(gate_w + (size_t)e * H)[j4];
      accs[e] = fmaf(xv.x, gv.x, accs[e]);
      accs[e] = fmaf(xv.y, gv.y, accs[e]);
      accs[e] = fmaf(xv.z, gv.z, accs[e]);
      accs[e] = fmaf(xv.w, gv.w, accs[e]);
    }
  }
#pragma unroll
  for (int e = 0; e < NEXP; ++e) {
    float v = accs[e];
#pragma unroll
    for (int off = 32; off > 0; off >>= 1) v += __shfl_down(v, off);
    accs[e] = v;
  }
  if (lane == 0) {
    float lg[NEXP];
#pragma unroll
    for (int e = 0; e < NEXP; ++e) lg[e] = fminf(fmaxf(accs[e], -50.f), 50.f);
    int e0 = 0; float w0 = lg[0];
#pragma unroll
    for (int e = 1; e < NEXP; ++e) { if (lg[e] > w0) { w0 = lg[e]; e0 = e; } }
    int e1 = -1; float w1 = -3.4e38f;
#pragma unroll
    for (int e = 0; e < NEXP; ++e) {
      if (e == e0) continue;
      if (lg[e] > w1) { w1 = lg[e]; e1 = e; }
    }
    const float r1 = expf(w1 - w0);  // <= 1
    float4 ti;
    ti.x = 1.f / (1.f + r1);
    ti.y = r1 / (1.f + r1);
    ti.z = __int_as_float(e0);
    ti.w = __int_as_float(e1);
    tokInfo[t] = ti;
  }
}

// ---------------- scatter: 4 tokens/block, wave = token ----------------
__global__ __launch_bounds__(256) void scatter_kernel(
    const float* __restrict__ x, const float* __restrict__ weighted,
    const int* __restrict__ mask_idx, const float4* __restrict__ tokInfo,
    float* __restrict__ out) {
  __shared__ float xrow[4][H];   // 32 KB
  __shared__ float acc[4][H];    // 32 KB
  const int tid  = threadIdx.x;
  const int wv   = tid >> 6;
  const int lane = tid & 63;
  const int t0   = blockIdx.x * 4;

  {
    const float4* xsrc = reinterpret_cast<const float4*>(x + (size_t)t0 * H);
    float4* xdst = reinterpret_cast<float4*>(&xrow[0][0]);
    float4* adst = reinterpret_cast<float4*>(&acc[0][0]);
    float4 z; z.x = z.y = z.z = z.w = 0.f;
#pragma unroll
    for (int i = 0; i < 8; ++i) {
      xdst[tid + i * 256] = xsrc[tid + i * 256];
      adst[tid + i * 256] = z;
    }
  }
  __syncthreads();

  const int t = t0 + wv;
  const float4 ti = tokInfo[t];
  const float rw0 = ti.x, rw1 = ti.y;
  const int e0 = __float_as_int(ti.z);
  const int e1 = __float_as_int(ti.w);

  const int4*   mask4 = reinterpret_cast<const int4*>(mask_idx);
  const float4* w0p4  = reinterpret_cast<const float4*>(weighted + (size_t)e0 * NS);
  const float4* w1p4  = reinterpret_cast<const float4*>(weighted + (size_t)e1 * NS);

  float* xw = &xrow[wv][0];
  float* aw = &acc[wv][0];

  int s4 = lane;
  int4   m = mask4[s4];
  float4 a = w0p4[s4];
  float4 b = w1p4[s4];
#pragma unroll 1
  for (int iter = 0; iter < 64; ++iter) {
    const int s4n = (s4 + 64 <= 4095) ? s4 + 64 : 4095;  // clamped prefetch
    int4   mN = mask4[s4n];
    float4 aN = w0p4[s4n];
    float4 bN = w1p4[s4n];

    float4 v;
    v.x = fmaf(rw0, a.x, rw1 * b.x);
    v.y = fmaf(rw0, a.y, rw1 * b.y);
    v.z = fmaf(rw0, a.z, rw1 * b.z);
    v.w = fmaf(rw0, a.w, rw1 * b.w);
    {
      int r = m.x >> LOGH, c = m.x & (H - 1);
      lds_add_f32(&aw[r], xw[c] * v.x);
    }
    {
      int r = m.y >> LOGH, c = m.y & (H - 1);
      lds_add_f32(&aw[r], xw[c] * v.y);
    }
    {
      int r = m.z >> LOGH, c = m.z & (H - 1);
      lds_add_f32(&aw[r], xw[c] * v.z);
    }
    {
      int r = m.w >> LOGH, c = m.w & (H - 1);
      lds_add_f32(&aw[r], xw[c] * v.w);
    }
    m = mN; a = aN; b = bN;
    s4 += 64;
  }
  // drain our asm ds ops before the barrier (compiler can't count them)
  asm volatile("s_waitcnt lgkmcnt(0)" ::: "memory");
  __syncthreads();

  {
    float4* orow = reinterpret_cast<float4*>(out + (size_t)t * H);
    const float4* arow = reinterpret_cast<const float4*>(aw);
#pragma unroll
    for (int i = 0; i < 8; ++i) {
      int idx = lane + i * 64;
      float4 o = orow[idx];
      float4 av = arow[idx];
      o.x += av.x; o.y += av.y; o.z += av.z; o.w += av.w;
      orow[idx] = o;
    }
  }
}

extern "C" void kernel_launch(void* const* d_in, const int* in_sizes, int n_in,
                              void* d_out, int out_size, void* d_ws, size_t ws_size,
                              hipStream_t stream) {
  const float* x          = (const float*)d_in[0];
  const float* gate_w     = (const float*)d_in[1];
  const float* W          = (const float*)d_in[2];
  const float* atoms      = (const float*)d_in[3];
  const float* eaw        = (const float*)d_in[4];
  const float* importance = (const float*)d_in[5];
  const int*   mask_idx   = (const int*)d_in[6];
  float* out = (float*)d_out;

  char* ws = (char*)d_ws;
  unsigned short* xb = (unsigned short*)ws;                                // 16 MB
  unsigned short* wb = (unsigned short*)(ws + (size_t)T_TOK * H * 2);      // 8 MB
  float* weighted = (float*)(ws + (size_t)T_TOK * H * 2 + (size_t)H * H * 2);  // 512 KB
  float4* tokInfo = (float4*)(ws + (size_t)T_TOK * H * 2 + (size_t)H * H * 2 +
                              (size_t)NEXP * NS * 4);                      // 64 KB

  cvt_kernel<<<2048, 256, 0, stream>>>(x, W, xb, wb);
  weighted_kernel<<<64, 256, 0, stream>>>(eaw, atoms, importance, weighted);
  gate_kernel<<<T_TOK / 4, 256, 0, stream>>>(x, gate_w, tokInfo);
  gemm_kernel<<<dim3(H / 128, T_TOK / 128), 256, 0, stream>>>(xb, wb, out);
  scatter_kernel<<<T_TOK / 4, 256, 0, stream>>>(x, weighted, mask_idx, tokInfo, out);
}

// Round 5
// 425.533 us; speedup vs baseline: 1.3331x; 1.3331x over previous
//
#include <hip/hip_runtime.h>
#include <hip/hip_bf16.h>
#include <stdint.h>

#define H       2048
#define LOGH    11
#define T_TOK   4096
#define NEXP    8
#define NATOM   64
#define NS      16384

typedef short bf16x8 __attribute__((ext_vector_type(8)));
typedef float f32x4  __attribute__((ext_vector_type(4)));

// native LDS float atomic add (fire-and-forget)
__device__ __forceinline__ void lds_add_f32(float* p, float v) {
  asm volatile("ds_add_f32 %0, %1"
               :
               : "v"((unsigned)(uintptr_t)p), "v"(v)
               : "memory");
}

// ---------------- convert x and W to bf16 (RNE) ----------------
__global__ __launch_bounds__(256) void cvt_kernel(
    const float* __restrict__ x, const float* __restrict__ W,
    unsigned short* __restrict__ xb, unsigned short* __restrict__ wb) {
  const int TH = T_TOK * H;
  const int WH = H * H;
  const int total4 = (TH + WH) / 4;
  for (int i = blockIdx.x * blockDim.x + threadIdx.x; i < total4;
       i += gridDim.x * blockDim.x) {
    int e0 = i * 4;
    const float* src;
    unsigned short* dst;
    if (e0 < TH) { src = x + e0; dst = xb + e0; }
    else         { src = W + (e0 - TH); dst = wb + (e0 - TH); }
    float4 v = *reinterpret_cast<const float4*>(src);
    ushort4 o;
    {
      union { float f; unsigned u; } c;
      c.f = v.x; c.u += 0x7fff + ((c.u >> 16) & 1); o.x = (unsigned short)(c.u >> 16);
      c.f = v.y; c.u += 0x7fff + ((c.u >> 16) & 1); o.y = (unsigned short)(c.u >> 16);
      c.f = v.z; c.u += 0x7fff + ((c.u >> 16) & 1); o.z = (unsigned short)(c.u >> 16);
      c.f = v.w; c.u += 0x7fff + ((c.u >> 16) & 1); o.w = (unsigned short)(c.u >> 16);
    }
    *reinterpret_cast<ushort4*>(dst) = o;
  }
}

// ---------------- weighted[e][s] = (softmax(eaw[e]) @ atoms)[s] * sigmoid(imp[e][s]) ----------------
__global__ __launch_bounds__(256) void weighted_kernel(
    const float* __restrict__ eaw, const float* __restrict__ atoms,
    const float* __restrict__ importance, float* __restrict__ weighted) {
  __shared__ float p[NATOM];
  const int e = blockIdx.x >> 3;
  const int chunk = blockIdx.x & 7;
  const int tid = threadIdx.x;
  if (tid < NATOM) p[tid] = eaw[e * NATOM + tid];
  __syncthreads();
  if (tid == 0) {
    float m = p[0];
    for (int a = 1; a < NATOM; ++a) m = fmaxf(m, p[a]);
    float s = 0.f;
    for (int a = 0; a < NATOM; ++a) { p[a] = expf(p[a] - m); s += p[a]; }
    float inv = 1.f / s;
    for (int a = 0; a < NATOM; ++a) p[a] *= inv;
  }
  __syncthreads();
  const int base = chunk * 2048 + tid;
  for (int it = 0; it < 8; ++it) {
    int s = base + it * 256;
    float acc = 0.f;
#pragma unroll 16
    for (int a = 0; a < NATOM; ++a) acc = fmaf(p[a], atoms[a * NS + s], acc);
    float imp = importance[e * NS + s];
    float sig = 1.f / (1.f + expf(-imp));
    weighted[e * NS + s] = acc * sig;
  }
}

// ---------------- build row-sorted, lane-transposed element list ----------------
// elemT[k*64 + l] = (r<<11)|c for sorted position pos = l*256 + k
// sidSorted[pos] = original s index (consumed by permute_weighted_kernel)
__global__ __launch_bounds__(1024) void build_sort_kernel(
    const int* __restrict__ mask_idx, int* __restrict__ elemT,
    int* __restrict__ sidSorted) {
  __shared__ int hist[H];
  __shared__ int base[H];
  __shared__ int wsum[16];
  __shared__ int wexc[16];
  const int tid = threadIdx.x;
  hist[tid] = 0;
  hist[tid + 1024] = 0;
  __syncthreads();
  for (int s = tid; s < NS; s += 1024) {
    int r = mask_idx[s] >> LOGH;
    atomicAdd(&hist[r], 1);
  }
  __syncthreads();
  // exclusive scan over 2048 counts (pairs per thread + wave scan + block combine)
  int a = hist[2 * tid], b = hist[2 * tid + 1];
  int ps = a + b;
  const int lane = tid & 63, wid = tid >> 6;
#pragma unroll
  for (int off = 1; off < 64; off <<= 1) {
    int n = __shfl_up(ps, off);
    if (lane >= off) ps += n;
  }
  if (lane == 63) wsum[wid] = ps;
  __syncthreads();
  if (tid == 0) {
    int run = 0;
    for (int w = 0; w < 16; ++w) { wexc[w] = run; run += wsum[w]; }
  }
  __syncthreads();
  int ex = wexc[wid] + ps - (a + b);
  base[2 * tid] = ex;
  base[2 * tid + 1] = ex + a;
  __syncthreads();
  for (int s = tid; s < NS; s += 1024) {
    int m = mask_idx[s];
    int r = m >> LOGH, c = m & (H - 1);
    int pos = atomicAdd(&base[r], 1);
    int l = pos >> 8, k = pos & 255;
    elemT[k * 64 + l] = (r << LOGH) | c;
    sidSorted[pos] = s;
  }
}

// ---------------- apply sort permutation (+transpose) to each expert's weighted row ----------------
__global__ __launch_bounds__(256) void permute_weighted_kernel(
    const float* __restrict__ weighted, const int* __restrict__ sidSorted,
    float* __restrict__ wSortedT) {
  const int i = blockIdx.x * 256 + threadIdx.x;  // sorted position
  const int e = blockIdx.y;
  const int s = sidSorted[i];
  const int outIdx = (i & 255) * 64 + (i >> 8);
  wSortedT[(size_t)e * NS + outIdx] = weighted[(size_t)e * NS + s];
}

// ---------------- bf16 MFMA GEMM: out[m][n] = sum_k xb[m][k] * wb[n][k] ----------------
__global__ __launch_bounds__(256) void gemm_kernel(
    const unsigned short* __restrict__ xb, const unsigned short* __restrict__ wb,
    float* __restrict__ out) {
  __shared__ __align__(16) unsigned short aLds[128 * 32];
  __shared__ __align__(16) unsigned short bLds[128 * 32];
  const int tid  = threadIdx.x;
  const int wave = tid >> 6;
  const int lane = tid & 63;
  const int m0 = blockIdx.y * 128;
  const int n0 = blockIdx.x * 128;
  const int wr = wave >> 1;
  const int wc = wave & 1;

  f32x4 acc[4][4];
#pragma unroll
  for (int i = 0; i < 4; ++i)
#pragma unroll
    for (int j = 0; j < 4; ++j)
#pragma unroll
      for (int r = 0; r < 4; ++r) acc[i][j][r] = 0.f;

  const int srow = lane >> 2;
  const int kcol = (lane & 3) * 8;

  for (int k0 = 0; k0 < H; k0 += 32) {
#pragma unroll
    for (int p = 0; p < 2; ++p) {
      const int g = p * 4 + wave;
      const unsigned short* ga = xb + (size_t)(m0 + g * 16 + srow) * H + k0 + kcol;
      const unsigned short* gb = wb + (size_t)(n0 + g * 16 + srow) * H + k0 + kcol;
      __builtin_amdgcn_global_load_lds(
          (const __attribute__((address_space(1))) unsigned int*)ga,
          (__attribute__((address_space(3))) unsigned int*)(aLds + g * 16 * 32), 16, 0, 0);
      __builtin_amdgcn_global_load_lds(
          (const __attribute__((address_space(1))) unsigned int*)gb,
          (__attribute__((address_space(3))) unsigned int*)(bLds + g * 16 * 32), 16, 0, 0);
    }
    __syncthreads();

    const int kc = (lane >> 4) * 8;
    const int ar = wr * 64 + (lane & 15);
    const int br = wc * 64 + (lane & 15);
    bf16x8 af[4], bfr[4];
#pragma unroll
    for (int i = 0; i < 4; ++i)
      af[i] = *reinterpret_cast<const bf16x8*>(aLds + (ar + i * 16) * 32 + kc);
#pragma unroll
    for (int j = 0; j < 4; ++j)
      bfr[j] = *reinterpret_cast<const bf16x8*>(bLds + (br + j * 16) * 32 + kc);
#pragma unroll
    for (int i = 0; i < 4; ++i)
#pragma unroll
      for (int j = 0; j < 4; ++j)
        acc[i][j] = __builtin_amdgcn_mfma_f32_16x16x32_bf16(af[i], bfr[j], acc[i][j], 0, 0, 0);
    __syncthreads();
  }

  const int cr = (lane >> 4) * 4;
  const int cc = lane & 15;
#pragma unroll
  for (int i = 0; i < 4; ++i)
#pragma unroll
    for (int j = 0; j < 4; ++j)
#pragma unroll
      for (int r = 0; r < 4; ++r)
        out[(size_t)(m0 + wr * 64 + i * 16 + cr + r) * H + (n0 + wc * 64 + j * 16 + cc)] =
            acc[i][j][r];
}

// ---------------- gate: one wave per token, exact fp32 top-2 ----------------
__global__ __launch_bounds__(256) void gate_kernel(
    const float* __restrict__ x, const float* __restrict__ gate_w,
    float4* __restrict__ tokInfo) {
  const int wv = threadIdx.x >> 6;
  const int lane = threadIdx.x & 63;
  const int t = blockIdx.x * 4 + wv;
  const float4* xr = reinterpret_cast<const float4*>(x + (size_t)t * H);

  float accs[NEXP];
#pragma unroll
  for (int e = 0; e < NEXP; ++e) accs[e] = 0.f;
#pragma unroll
  for (int it = 0; it < 8; ++it) {
    const int j4 = it * 64 + lane;
    float4 xv = xr[j4];
#pragma unroll
    for (int e = 0; e < NEXP; ++e) {
      float4 gv = reinterpret_cast<const float4*>(gate_w + (size_t)e * H)[j4];
      accs[e] = fmaf(xv.x, gv.x, accs[e]);
      accs[e] = fmaf(xv.y, gv.y, accs[e]);
      accs[e] = fmaf(xv.z, gv.z, accs[e]);
      accs[e] = fmaf(xv.w, gv.w, accs[e]);
    }
  }
#pragma unroll
  for (int e = 0; e < NEXP; ++e) {
    float v = accs[e];
#pragma unroll
    for (int off = 32; off > 0; off >>= 1) v += __shfl_down(v, off);
    accs[e] = v;
  }
  if (lane == 0) {
    float lg[NEXP];
#pragma unroll
    for (int e = 0; e < NEXP; ++e) lg[e] = fminf(fmaxf(accs[e], -50.f), 50.f);
    int e0 = 0; float w0 = lg[0];
#pragma unroll
    for (int e = 1; e < NEXP; ++e) { if (lg[e] > w0) { w0 = lg[e]; e0 = e; } }
    int e1 = -1; float w1 = -3.4e38f;
#pragma unroll
    for (int e = 0; e < NEXP; ++e) {
      if (e == e0) continue;
      if (lg[e] > w1) { w1 = lg[e]; e1 = e; }
    }
    const float r1 = expf(w1 - w0);  // <= 1
    float4 ti;
    ti.x = 1.f / (1.f + r1);
    ti.y = r1 / (1.f + r1);
    ti.z = __int_as_float(e0);
    ti.w = __int_as_float(e1);
    tokInfo[t] = ti;
  }
}

// ---------------- scatter v2: row-sorted streams, register accumulate, no bulk atomics ----------------
__global__ __launch_bounds__(256) void scatter_kernel(
    const float* __restrict__ x, const float* __restrict__ wSortedT,
    const int* __restrict__ elemT, const float4* __restrict__ tokInfo,
    float* __restrict__ out) {
  __shared__ float xrow[4][H];   // 32 KB
  __shared__ float acc[4][H];    // 32 KB
  const int tid  = threadIdx.x;
  const int wv   = tid >> 6;
  const int lane = tid & 63;
  const int t0   = blockIdx.x * 4;

  {
    const float4* xsrc = reinterpret_cast<const float4*>(x + (size_t)t0 * H);
    float4* xdst = reinterpret_cast<float4*>(&xrow[0][0]);
    float4* adst = reinterpret_cast<float4*>(&acc[0][0]);
    float4 z; z.x = z.y = z.z = z.w = 0.f;
#pragma unroll
    for (int i = 0; i < 8; ++i) {
      xdst[tid + i * 256] = xsrc[tid + i * 256];
      adst[tid + i * 256] = z;
    }
  }
  __syncthreads();

  const int t = t0 + wv;
  const float4 ti = tokInfo[t];
  const float rw0 = ti.x, rw1 = ti.y;
  const int e0 = __float_as_int(ti.z);
  const int e1 = __float_as_int(ti.w);

  const float* w0T = wSortedT + (size_t)e0 * NS;
  const float* w1T = wSortedT + (size_t)e1 * NS;
  float* xw = &xrow[wv][0];
  float* aw = &acc[wv][0];

  // lane owns sorted positions [lane*256, lane*256+256) presented transposed:
  // slot k -> index k*64+lane (coalesced). Rows are contiguous runs; interior
  // rows are exclusively owned -> plain ds_write; first & final flush may share
  // a row with neighbor lanes -> ds_add_f32 (<=2 atomics/lane).
  float accv = 0.f;
  int curR = -1;
  int flushed = 0;
#pragma unroll 4
  for (int k = 0; k < 256; ++k) {
    const int idx = k * 64 + lane;
    const int ev = elemT[idx];
    const float w0 = w0T[idx];
    const float w1 = w1T[idx];
    const int r = ev >> LOGH;
    const int c = ev & (H - 1);
    const float val = fmaf(rw0, w0, rw1 * w1);
    const float ct = xw[c] * val;
    if (r != curR) {
      if (curR >= 0) {
        if (flushed) aw[curR] = accv;
        else { lds_add_f32(&aw[curR], accv); flushed = 1; }
      }
      curR = r;
      accv = ct;
    } else {
      accv += ct;
    }
  }
  lds_add_f32(&aw[curR], accv);  // final flush (may share row with next lane)
  asm volatile("s_waitcnt lgkmcnt(0)" ::: "memory");
  __syncthreads();

  {
    float4* orow = reinterpret_cast<float4*>(out + (size_t)t * H);
    const float4* arow = reinterpret_cast<const float4*>(aw);
#pragma unroll
    for (int i = 0; i < 8; ++i) {
      int idx = lane + i * 64;
      float4 o = orow[idx];
      float4 av = arow[idx];
      o.x += av.x; o.y += av.y; o.z += av.z; o.w += av.w;
      orow[idx] = o;
    }
  }
}

extern "C" void kernel_launch(void* const* d_in, const int* in_sizes, int n_in,
                              void* d_out, int out_size, void* d_ws, size_t ws_size,
                              hipStream_t stream) {
  const float* x          = (const float*)d_in[0];
  const float* gate_w     = (const float*)d_in[1];
  const float* W          = (const float*)d_in[2];
  const float* atoms      = (const float*)d_in[3];
  const float* eaw        = (const float*)d_in[4];
  const float* importance = (const float*)d_in[5];
  const int*   mask_idx   = (const int*)d_in[6];
  float* out = (float*)d_out;

  char* ws = (char*)d_ws;
  size_t off = 0;
  unsigned short* xb = (unsigned short*)(ws + off); off += (size_t)T_TOK * H * 2;  // 16 MB
  unsigned short* wb = (unsigned short*)(ws + off); off += (size_t)H * H * 2;      // 8 MB
  float* weighted    = (float*)(ws + off);          off += (size_t)NEXP * NS * 4;  // 512 KB
  float4* tokInfo    = (float4*)(ws + off);         off += (size_t)T_TOK * 16;     // 64 KB
  int* elemT         = (int*)(ws + off);            off += (size_t)NS * 4;         // 64 KB
  int* sidSorted     = (int*)(ws + off);            off += (size_t)NS * 4;         // 64 KB
  float* wSortedT    = (float*)(ws + off);          off += (size_t)NEXP * NS * 4;  // 512 KB

  cvt_kernel<<<2048, 256, 0, stream>>>(x, W, xb, wb);
  weighted_kernel<<<64, 256, 0, stream>>>(eaw, atoms, importance, weighted);
  build_sort_kernel<<<1, 1024, 0, stream>>>(mask_idx, elemT, sidSorted);
  permute_weighted_kernel<<<dim3(NS / 256, NEXP), 256, 0, stream>>>(weighted, sidSorted, wSortedT);
  gate_kernel<<<T_TOK / 4, 256, 0, stream>>>(x, gate_w, tokInfo);
  gemm_kernel<<<dim3(H / 128, T_TOK / 128), 256, 0, stream>>>(xb, wb, out);
  scatter_kernel<<<T_TOK / 4, 256, 0, stream>>>(x, wSortedT, elemT, tokInfo, out);
}

// Round 6
// 317.865 us; speedup vs baseline: 1.7847x; 1.3387x over previous
//
#include <hip/hip_runtime.h>
#include <hip/hip_bf16.h>
#include <stdint.h>

#define H       2048
#define LOGH    11
#define T_TOK   4096
#define NEXP    8
#define NATOM   64
#define NS      16384

typedef short bf16x8 __attribute__((ext_vector_type(8)));
typedef float f32x4  __attribute__((ext_vector_type(4)));

// ---------------- convert x and W to bf16 (RNE) ----------------
__global__ __launch_bounds__(256) void cvt_kernel(
    const float* __restrict__ x, const float* __restrict__ W,
    unsigned short* __restrict__ xb, unsigned short* __restrict__ wb) {
  const int TH = T_TOK * H;
  const int WH = H * H;
  const int total4 = (TH + WH) / 4;
  for (int i = blockIdx.x * blockDim.x + threadIdx.x; i < total4;
       i += gridDim.x * blockDim.x) {
    int e0 = i * 4;
    const float* src;
    unsigned short* dst;
    if (e0 < TH) { src = x + e0; dst = xb + e0; }
    else         { src = W + (e0 - TH); dst = wb + (e0 - TH); }
    float4 v = *reinterpret_cast<const float4*>(src);
    ushort4 o;
    {
      union { float f; unsigned u; } c;
      c.f = v.x; c.u += 0x7fff + ((c.u >> 16) & 1); o.x = (unsigned short)(c.u >> 16);
      c.f = v.y; c.u += 0x7fff + ((c.u >> 16) & 1); o.y = (unsigned short)(c.u >> 16);
      c.f = v.z; c.u += 0x7fff + ((c.u >> 16) & 1); o.z = (unsigned short)(c.u >> 16);
      c.f = v.w; c.u += 0x7fff + ((c.u >> 16) & 1); o.w = (unsigned short)(c.u >> 16);
    }
    *reinterpret_cast<ushort4*>(dst) = o;
  }
}

// ---------------- weighted[e][s] = (softmax(eaw[e]) @ atoms)[s] * sigmoid(imp[e][s]) ----------------
__global__ __launch_bounds__(256) void weighted_kernel(
    const float* __restrict__ eaw, const float* __restrict__ atoms,
    const float* __restrict__ importance, float* __restrict__ weighted) {
  __shared__ float p[NATOM];
  const int e = blockIdx.x >> 3;
  const int chunk = blockIdx.x & 7;
  const int tid = threadIdx.x;
  if (tid < NATOM) p[tid] = eaw[e * NATOM + tid];
  __syncthreads();
  if (tid == 0) {
    float m = p[0];
    for (int a = 1; a < NATOM; ++a) m = fmaxf(m, p[a]);
    float s = 0.f;
    for (int a = 0; a < NATOM; ++a) { p[a] = expf(p[a] - m); s += p[a]; }
    float inv = 1.f / s;
    for (int a = 0; a < NATOM; ++a) p[a] *= inv;
  }
  __syncthreads();
  const int base = chunk * 2048 + tid;
  for (int it = 0; it < 8; ++it) {
    int s = base + it * 256;
    float acc = 0.f;
#pragma unroll 16
    for (int a = 0; a < NATOM; ++a) acc = fmaf(p[a], atoms[a * NS + s], acc);
    float imp = importance[e * NS + s];
    float sig = 1.f / (1.f + expf(-imp));
    weighted[e * NS + s] = acc * sig;
  }
}

// ---------------- build row-sorted, lane-transposed element list ----------------
// elemT[k*64 + l] = (r<<11)|c for sorted position pos = l*256 + k
// sidSorted[pos] = original s index (consumed by permute_weighted_kernel)
__global__ __launch_bounds__(1024) void build_sort_kernel(
    const int* __restrict__ mask_idx, int* __restrict__ elemT,
    int* __restrict__ sidSorted) {
  __shared__ int hist[H];
  __shared__ int base[H];
  __shared__ int wsum[16];
  __shared__ int wexc[16];
  const int tid = threadIdx.x;
  hist[tid] = 0;
  hist[tid + 1024] = 0;
  __syncthreads();
  for (int s = tid; s < NS; s += 1024) {
    int r = mask_idx[s] >> LOGH;
    atomicAdd(&hist[r], 1);
  }
  __syncthreads();
  int a = hist[2 * tid], b = hist[2 * tid + 1];
  int ps = a + b;
  const int lane = tid & 63, wid = tid >> 6;
#pragma unroll
  for (int off = 1; off < 64; off <<= 1) {
    int n = __shfl_up(ps, off);
    if (lane >= off) ps += n;
  }
  if (lane == 63) wsum[wid] = ps;
  __syncthreads();
  if (tid == 0) {
    int run = 0;
    for (int w = 0; w < 16; ++w) { wexc[w] = run; run += wsum[w]; }
  }
  __syncthreads();
  int ex = wexc[wid] + ps - (a + b);
  base[2 * tid] = ex;
  base[2 * tid + 1] = ex + a;
  __syncthreads();
  for (int s = tid; s < NS; s += 1024) {
    int m = mask_idx[s];
    int r = m >> LOGH, c = m & (H - 1);
    int pos = atomicAdd(&base[r], 1);
    int l = pos >> 8, k = pos & 255;
    elemT[k * 64 + l] = (r << LOGH) | c;
    sidSorted[pos] = s;
  }
}

// ---------------- apply sort permutation (+transpose) to each expert's weighted row ----------------
__global__ __launch_bounds__(256) void permute_weighted_kernel(
    const float* __restrict__ weighted, const int* __restrict__ sidSorted,
    float* __restrict__ wSortedT) {
  const int i = blockIdx.x * 256 + threadIdx.x;  // sorted position
  const int e = blockIdx.y;
  const int s = sidSorted[i];
  const int outIdx = (i & 255) * 64 + (i >> 8);
  wSortedT[(size_t)e * NS + outIdx] = weighted[(size_t)e * NS + s];
}

// ---------------- bf16 MFMA GEMM: out[m][n] = sum_k xb[m][k] * wb[n][k] ----------------
__global__ __launch_bounds__(256) void gemm_kernel(
    const unsigned short* __restrict__ xb, const unsigned short* __restrict__ wb,
    float* __restrict__ out) {
  __shared__ __align__(16) unsigned short aLds[128 * 32];
  __shared__ __align__(16) unsigned short bLds[128 * 32];
  const int tid  = threadIdx.x;
  const int wave = tid >> 6;
  const int lane = tid & 63;
  const int m0 = blockIdx.y * 128;
  const int n0 = blockIdx.x * 128;
  const int wr = wave >> 1;
  const int wc = wave & 1;

  f32x4 acc[4][4];
#pragma unroll
  for (int i = 0; i < 4; ++i)
#pragma unroll
    for (int j = 0; j < 4; ++j)
#pragma unroll
      for (int r = 0; r < 4; ++r) acc[i][j][r] = 0.f;

  const int srow = lane >> 2;
  const int kcol = (lane & 3) * 8;

  for (int k0 = 0; k0 < H; k0 += 32) {
#pragma unroll
    for (int p = 0; p < 2; ++p) {
      const int g = p * 4 + wave;
      const unsigned short* ga = xb + (size_t)(m0 + g * 16 + srow) * H + k0 + kcol;
      const unsigned short* gb = wb + (size_t)(n0 + g * 16 + srow) * H + k0 + kcol;
      __builtin_amdgcn_global_load_lds(
          (const __attribute__((address_space(1))) unsigned int*)ga,
          (__attribute__((address_space(3))) unsigned int*)(aLds + g * 16 * 32), 16, 0, 0);
      __builtin_amdgcn_global_load_lds(
          (const __attribute__((address_space(1))) unsigned int*)gb,
          (__attribute__((address_space(3))) unsigned int*)(bLds + g * 16 * 32), 16, 0, 0);
    }
    __syncthreads();

    const int kc = (lane >> 4) * 8;
    const int ar = wr * 64 + (lane & 15);
    const int br = wc * 64 + (lane & 15);
    bf16x8 af[4], bfr[4];
#pragma unroll
    for (int i = 0; i < 4; ++i)
      af[i] = *reinterpret_cast<const bf16x8*>(aLds + (ar + i * 16) * 32 + kc);
#pragma unroll
    for (int j = 0; j < 4; ++j)
      bfr[j] = *reinterpret_cast<const bf16x8*>(bLds + (br + j * 16) * 32 + kc);
#pragma unroll
    for (int i = 0; i < 4; ++i)
#pragma unroll
      for (int j = 0; j < 4; ++j)
        acc[i][j] = __builtin_amdgcn_mfma_f32_16x16x32_bf16(af[i], bfr[j], acc[i][j], 0, 0, 0);
    __syncthreads();
  }

  const int cr = (lane >> 4) * 4;
  const int cc = lane & 15;
#pragma unroll
  for (int i = 0; i < 4; ++i)
#pragma unroll
    for (int j = 0; j < 4; ++j)
#pragma unroll
      for (int r = 0; r < 4; ++r)
        out[(size_t)(m0 + wr * 64 + i * 16 + cr + r) * H + (n0 + wc * 64 + j * 16 + cc)] =
            acc[i][j][r];
}

// ---------------- gate: one wave per token, exact fp32 top-2 ----------------
__global__ __launch_bounds__(256) void gate_kernel(
    const float* __restrict__ x, const float* __restrict__ gate_w,
    float4* __restrict__ tokInfo) {
  const int wv = threadIdx.x >> 6;
  const int lane = threadIdx.x & 63;
  const int t = blockIdx.x * 4 + wv;
  const float4* xr = reinterpret_cast<const float4*>(x + (size_t)t * H);

  float accs[NEXP];
#pragma unroll
  for (int e = 0; e < NEXP; ++e) accs[e] = 0.f;
#pragma unroll
  for (int it = 0; it < 8; ++it) {
    const int j4 = it * 64 + lane;
    float4 xv = xr[j4];
#pragma unroll
    for (int e = 0; e < NEXP; ++e) {
      float4 gv = reinterpret_cast<const float4*>(gate_w + (size_t)e * H)[j4];
      accs[e] = fmaf(xv.x, gv.x, accs[e]);
      accs[e] = fmaf(xv.y, gv.y, accs[e]);
      accs[e] = fmaf(xv.z, gv.z, accs[e]);
      accs[e] = fmaf(xv.w, gv.w, accs[e]);
    }
  }
#pragma unroll
  for (int e = 0; e < NEXP; ++e) {
    float v = accs[e];
#pragma unroll
    for (int off = 32; off > 0; off >>= 1) v += __shfl_down(v, off);
    accs[e] = v;
  }
  if (lane == 0) {
    float lg[NEXP];
#pragma unroll
    for (int e = 0; e < NEXP; ++e) lg[e] = fminf(fmaxf(accs[e], -50.f), 50.f);
    int e0 = 0; float w0 = lg[0];
#pragma unroll
    for (int e = 1; e < NEXP; ++e) { if (lg[e] > w0) { w0 = lg[e]; e0 = e; } }
    int e1 = -1; float w1 = -3.4e38f;
#pragma unroll
    for (int e = 0; e < NEXP; ++e) {
      if (e == e0) continue;
      if (lg[e] > w1) { w1 = lg[e]; e1 = e; }
    }
    const float r1 = expf(w1 - w0);  // <= 1
    float4 ti;
    ti.x = 1.f / (1.f + r1);
    ti.y = r1 / (1.f + r1);
    ti.z = __int_as_float(e0);
    ti.w = __int_as_float(e1);
    tokInfo[t] = ti;
  }
}

// ---------------- scatter v3: sorted streams + explicit software pipeline ----------------
// 2 groups of 8 slots per iteration; globals prefetched 1 iteration ahead,
// all 16 LDS gathers issued before processing. Critical path = fma chain only.
__global__ __launch_bounds__(256) void scatter_kernel(
    const float* __restrict__ x, const float* __restrict__ wSortedT,
    const int* __restrict__ elemT, const float4* __restrict__ tokInfo,
    float* __restrict__ out) {
  __shared__ float xrow[4][H];   // 32 KB
  __shared__ float acc[4][H];    // 32 KB
  const int tid  = threadIdx.x;
  const int wv   = tid >> 6;
  const int lane = tid & 63;
  const int t0   = blockIdx.x * 4;

  {
    const float4* xsrc = reinterpret_cast<const float4*>(x + (size_t)t0 * H);
    float4* xdst = reinterpret_cast<float4*>(&xrow[0][0]);
    float4* adst = reinterpret_cast<float4*>(&acc[0][0]);
    float4 z; z.x = z.y = z.z = z.w = 0.f;
#pragma unroll
    for (int i = 0; i < 8; ++i) {
      xdst[tid + i * 256] = xsrc[tid + i * 256];
      adst[tid + i * 256] = z;
    }
  }
  __syncthreads();

  const int t = t0 + wv;
  const float4 ti = tokInfo[t];
  const float rw0 = ti.x, rw1 = ti.y;
  const int e0 = __float_as_int(ti.z);
  const int e1 = __float_as_int(ti.w);

  const float* w0T = wSortedT + (size_t)e0 * NS;
  const float* w1T = wSortedT + (size_t)e1 * NS;
  float* xw = &xrow[wv][0];
  float* aw = &acc[wv][0];

  // pipeline buffers (statically indexed only)
  int   evA[8], evB[8], evA2[8], evB2[8];
  float w0A[8], w0B[8], w0A2[8], w0B2[8];
  float w1A[8], w1B[8], w1A2[8], w1B2[8];
  float xvA[8], xvB[8];

#define LOADG(dev, dw0, dw1, g)                                   \
  _Pragma("unroll")                                               \
  for (int j = 0; j < 8; ++j) {                                   \
    const int idx = (g) * 512 + j * 64 + lane;                    \
    dev[j] = elemT[idx];                                          \
    dw0[j] = w0T[idx];                                            \
    dw1[j] = w1T[idx];                                            \
  }

#define GATHER(xv, ev)                                            \
  _Pragma("unroll")                                               \
  for (int j = 0; j < 8; ++j) xv[j] = xw[ev[j] & (H - 1)];

#define PROCESS(ev, w0a, w1a, xv)                                 \
  _Pragma("unroll")                                               \
  for (int j = 0; j < 8; ++j) {                                   \
    const int r = ev[j] >> LOGH;                                  \
    const float val = fmaf(rw0, w0a[j], rw1 * w1a[j]);            \
    const float ct = xv[j] * val;                                 \
    if (r != curR) {                                              \
      if (curR >= 0) {                                            \
        if (flushed) aw[curR] = accv;                             \
        else { atomicAdd(&aw[curR], accv); flushed = 1; }         \
      }                                                           \
      curR = r; accv = ct;                                        \
    } else {                                                      \
      accv += ct;                                                 \
    }                                                             \
  }

  LOADG(evA, w0A, w1A, 0)
  LOADG(evB, w0B, w1B, 1)

  float accv = 0.f;
  int curR = -1;
  int flushed = 0;

#pragma unroll 2
  for (int i = 0; i < 16; ++i) {
    const int gA2 = (2 * i + 2 <= 31) ? 2 * i + 2 : 30;
    const int gB2 = (2 * i + 3 <= 31) ? 2 * i + 3 : 31;
    LOADG(evA2, w0A2, w1A2, gA2)
    LOADG(evB2, w0B2, w1B2, gB2)
    GATHER(xvA, evA)
    GATHER(xvB, evB)
    PROCESS(evA, w0A, w1A, xvA)
    PROCESS(evB, w0B, w1B, xvB)
#pragma unroll
    for (int j = 0; j < 8; ++j) {
      evA[j] = evA2[j]; w0A[j] = w0A2[j]; w1A[j] = w1A2[j];
      evB[j] = evB2[j]; w0B[j] = w0B2[j]; w1B[j] = w1B2[j];
    }
  }
  atomicAdd(&aw[curR], accv);  // final flush (may share row with next lane)
  __syncthreads();

  {
    float4* orow = reinterpret_cast<float4*>(out + (size_t)t * H);
    const float4* arow = reinterpret_cast<const float4*>(aw);
#pragma unroll
    for (int i = 0; i < 8; ++i) {
      int idx = lane + i * 64;
      float4 o = orow[idx];
      float4 av = arow[idx];
      o.x += av.x; o.y += av.y; o.z += av.z; o.w += av.w;
      orow[idx] = o;
    }
  }
#undef LOADG
#undef GATHER
#undef PROCESS
}

extern "C" void kernel_launch(void* const* d_in, const int* in_sizes, int n_in,
                              void* d_out, int out_size, void* d_ws, size_t ws_size,
                              hipStream_t stream) {
  const float* x          = (const float*)d_in[0];
  const float* gate_w     = (const float*)d_in[1];
  const float* W          = (const float*)d_in[2];
  const float* atoms      = (const float*)d_in[3];
  const float* eaw        = (const float*)d_in[4];
  const float* importance = (const float*)d_in[5];
  const int*   mask_idx   = (const int*)d_in[6];
  float* out = (float*)d_out;

  char* ws = (char*)d_ws;
  size_t off = 0;
  unsigned short* xb = (unsigned short*)(ws + off); off += (size_t)T_TOK * H * 2;  // 16 MB
  unsigned short* wb = (unsigned short*)(ws + off); off += (size_t)H * H * 2;      // 8 MB
  float* weighted    = (float*)(ws + off);          off += (size_t)NEXP * NS * 4;  // 512 KB
  float4* tokInfo    = (float4*)(ws + off);         off += (size_t)T_TOK * 16;     // 64 KB
  int* elemT         = (int*)(ws + off);            off += (size_t)NS * 4;         // 64 KB
  int* sidSorted     = (int*)(ws + off);            off += (size_t)NS * 4;         // 64 KB
  float* wSortedT    = (float*)(ws + off);          off += (size_t)NEXP * NS * 4;  // 512 KB

  cvt_kernel<<<2048, 256, 0, stream>>>(x, W, xb, wb);
  weighted_kernel<<<64, 256, 0, stream>>>(eaw, atoms, importance, weighted);
  build_sort_kernel<<<1, 1024, 0, stream>>>(mask_idx, elemT, sidSorted);
  permute_weighted_kernel<<<dim3(NS / 256, NEXP), 256, 0, stream>>>(weighted, sidSorted, wSortedT);
  gate_kernel<<<T_TOK / 4, 256, 0, stream>>>(x, gate_w, tokInfo);
  gemm_kernel<<<dim3(H / 128, T_TOK / 128), 256, 0, stream>>>(xb, wb, out);
  scatter_kernel<<<T_TOK / 4, 256, 0, stream>>>(x, wSortedT, elemT, tokInfo, out);
}

// Round 8
// 285.567 us; speedup vs baseline: 1.9865x; 1.1131x over previous
//
#include <hip/hip_runtime.h>
#include <hip/hip_bf16.h>
#include <stdint.h>

#define H       2048
#define LOGH    11
#define T_TOK   4096
#define NEXP    8
#define NATOM   64
#define NS      16384

typedef short bf16x8 __attribute__((ext_vector_type(8)));
typedef float f32x4  __attribute__((ext_vector_type(4)));

__device__ __forceinline__ unsigned short f2bf(float f) {
  union { float f; unsigned u; } c;
  c.f = f;
  c.u += 0x7fff + ((c.u >> 16) & 1);
  return (unsigned short)(c.u >> 16);
}

// ---------------- prep: gate (wave/token) + x->bf16 fused; separate blocks cvt W ----------------
__global__ __launch_bounds__(256) void prep_kernel(
    const float* __restrict__ x, const float* __restrict__ gate_w,
    const float* __restrict__ W, unsigned short* __restrict__ xb,
    unsigned short* __restrict__ wb, float4* __restrict__ tokInfo) {
  const int b = blockIdx.x;
  if (b >= T_TOK / 4) {
    // W conversion: 512 blocks x 256 threads x 8 float4
    const int wblk = b - T_TOK / 4;
    const float4* src = reinterpret_cast<const float4*>(W);
#pragma unroll
    for (int p = 0; p < 8; ++p) {
      const int i = (wblk + p * 512) * 256 + threadIdx.x;
      float4 v = src[i];
      ushort4 o;
      o.x = f2bf(v.x); o.y = f2bf(v.y); o.z = f2bf(v.z); o.w = f2bf(v.w);
      *reinterpret_cast<ushort4*>(wb + (size_t)i * 4) = o;
    }
    return;
  }
  const int wv = threadIdx.x >> 6;
  const int lane = threadIdx.x & 63;
  const int t = b * 4 + wv;
  const float4* xr = reinterpret_cast<const float4*>(x + (size_t)t * H);
  unsigned short* xbr = xb + (size_t)t * H;

  float accs[NEXP];
#pragma unroll
  for (int e = 0; e < NEXP; ++e) accs[e] = 0.f;
#pragma unroll
  for (int it = 0; it < 8; ++it) {
    const int j4 = it * 64 + lane;
    float4 xv = xr[j4];
    // free bf16 conversion of the row we already loaded
    ushort4 o;
    o.x = f2bf(xv.x); o.y = f2bf(xv.y); o.z = f2bf(xv.z); o.w = f2bf(xv.w);
    *reinterpret_cast<ushort4*>(xbr + (size_t)j4 * 4) = o;
#pragma unroll
    for (int e = 0; e < NEXP; ++e) {
      float4 gv = reinterpret_cast<const float4*>(gate_w + (size_t)e * H)[j4];
      accs[e] = fmaf(xv.x, gv.x, accs[e]);
      accs[e] = fmaf(xv.y, gv.y, accs[e]);
      accs[e] = fmaf(xv.z, gv.z, accs[e]);
      accs[e] = fmaf(xv.w, gv.w, accs[e]);
    }
  }
#pragma unroll
  for (int e = 0; e < NEXP; ++e) {
    float v = accs[e];
#pragma unroll
    for (int off = 32; off > 0; off >>= 1) v += __shfl_down(v, off);
    accs[e] = v;
  }
  if (lane == 0) {
    float lg[NEXP];
#pragma unroll
    for (int e = 0; e < NEXP; ++e) lg[e] = fminf(fmaxf(accs[e], -50.f), 50.f);
    int e0 = 0; float w0 = lg[0];
#pragma unroll
    for (int e = 1; e < NEXP; ++e) { if (lg[e] > w0) { w0 = lg[e]; e0 = e; } }
    int e1 = -1; float w1 = -3.4e38f;
#pragma unroll
    for (int e = 0; e < NEXP; ++e) {
      if (e == e0) continue;
      if (lg[e] > w1) { w1 = lg[e]; e1 = e; }
    }
    const float r1 = expf(w1 - w0);  // <= 1
    float4 ti;
    ti.x = 1.f / (1.f + r1);
    ti.y = r1 / (1.f + r1);
    ti.z = __int_as_float(e0);
    ti.w = __int_as_float(e1);
    tokInfo[t] = ti;
  }
}

// ---------------- weighted[e][s] = (softmax(eaw[e]) @ atoms)[s] * sigmoid(imp[e][s]) ----------------
__global__ __launch_bounds__(256) void weighted_kernel(
    const float* __restrict__ eaw, const float* __restrict__ atoms,
    const float* __restrict__ importance, float* __restrict__ weighted) {
  __shared__ float p[NATOM];
  const int e = blockIdx.x >> 3;
  const int chunk = blockIdx.x & 7;
  const int tid = threadIdx.x;
  if (tid < NATOM) p[tid] = eaw[e * NATOM + tid];
  __syncthreads();
  if (tid == 0) {
    float m = p[0];
    for (int a = 1; a < NATOM; ++a) m = fmaxf(m, p[a]);
    float s = 0.f;
    for (int a = 0; a < NATOM; ++a) { p[a] = expf(p[a] - m); s += p[a]; }
    float inv = 1.f / s;
    for (int a = 0; a < NATOM; ++a) p[a] *= inv;
  }
  __syncthreads();
  const int base = chunk * 2048 + tid;
  for (int it = 0; it < 8; ++it) {
    int s = base + it * 256;
    float acc = 0.f;
#pragma unroll 16
    for (int a = 0; a < NATOM; ++a) acc = fmaf(p[a], atoms[a * NS + s], acc);
    float imp = importance[e * NS + s];
    float sig = 1.f / (1.f + expf(-imp));
    weighted[e * NS + s] = acc * sig;
  }
}

// ---------------- build row-sorted element list, 128-lane vec4 transposed layout ----------------
// sorted position pos: lane l = pos>>7 owns run [l*128, l*128+128)
// flat index = ((k>>2)<<9) | (l<<2) | (k&3)   where k = pos&127  (vec4-packed per lane)
__device__ __forceinline__ int sortedFlat(int pos) {
  const int l = pos >> 7, k = pos & 127;
  return ((k >> 2) << 9) | (l << 2) | (k & 3);
}

__global__ __launch_bounds__(1024) void build_sort_kernel(
    const int* __restrict__ mask_idx, int* __restrict__ elemT,
    int* __restrict__ sidSorted) {
  __shared__ int hist[H];
  __shared__ int base[H];
  __shared__ int wsum[16];
  __shared__ int wexc[16];
  const int tid = threadIdx.x;
  hist[tid] = 0;
  hist[tid + 1024] = 0;
  __syncthreads();
  for (int s = tid; s < NS; s += 1024) {
    int r = mask_idx[s] >> LOGH;
    atomicAdd(&hist[r], 1);
  }
  __syncthreads();
  int a = hist[2 * tid], b = hist[2 * tid + 1];
  int ps = a + b;
  const int lane = tid & 63, wid = tid >> 6;
#pragma unroll
  for (int off = 1; off < 64; off <<= 1) {
    int n = __shfl_up(ps, off);
    if (lane >= off) ps += n;
  }
  if (lane == 63) wsum[wid] = ps;
  __syncthreads();
  if (tid == 0) {
    int run = 0;
    for (int w = 0; w < 16; ++w) { wexc[w] = run; run += wsum[w]; }
  }
  __syncthreads();
  int ex = wexc[wid] + ps - (a + b);
  base[2 * tid] = ex;
  base[2 * tid + 1] = ex + a;
  __syncthreads();
  for (int s = tid; s < NS; s += 1024) {
    int m = mask_idx[s];
    int r = m >> LOGH, c = m & (H - 1);
    int pos = atomicAdd(&base[r], 1);
    elemT[sortedFlat(pos)] = (r << LOGH) | c;
    sidSorted[pos] = s;
  }
}

// ---------------- apply sort permutation (+vec4 transpose) to each expert's weighted row ----------------
__global__ __launch_bounds__(256) void permute_weighted_kernel(
    const float* __restrict__ weighted, const int* __restrict__ sidSorted,
    float* __restrict__ wSortedT) {
  const int i = blockIdx.x * 256 + threadIdx.x;  // sorted position
  const int e = blockIdx.y;
  const int s = sidSorted[i];
  wSortedT[(size_t)e * NS + sortedFlat(i)] = weighted[(size_t)e * NS + s];
}

// ---------------- bf16 MFMA GEMM with XCD-aware swizzle ----------------
__global__ __launch_bounds__(256) void gemm_kernel(
    const unsigned short* __restrict__ xb, const unsigned short* __restrict__ wb,
    float* __restrict__ out) {
  __shared__ __align__(16) unsigned short aLds[128 * 32];
  __shared__ __align__(16) unsigned short bLds[128 * 32];
  const int tid  = threadIdx.x;
  const int wave = tid >> 6;
  const int lane = tid & 63;
  // XCD swizzle: xcd k = bid&7 gets n-tiles {2k,2k+1} x all 32 m-tiles
  const int bid = blockIdx.x;
  const int xcd = bid & 7;
  const int j   = bid >> 3;            // 0..63
  const int n_t = (xcd << 1) | (j & 1);
  const int m_t = j >> 1;
  const int m0 = m_t * 128;
  const int n0 = n_t * 128;
  const int wr = wave >> 1;
  const int wc = wave & 1;

  f32x4 acc[4][4];
#pragma unroll
  for (int i = 0; i < 4; ++i)
#pragma unroll
    for (int jj = 0; jj < 4; ++jj)
#pragma unroll
      for (int r = 0; r < 4; ++r) acc[i][jj][r] = 0.f;

  const int srow = lane >> 2;
  const int kcol = (lane & 3) * 8;

  for (int k0 = 0; k0 < H; k0 += 32) {
#pragma unroll
    for (int p = 0; p < 2; ++p) {
      const int g = p * 4 + wave;
      const unsigned short* ga = xb + (size_t)(m0 + g * 16 + srow) * H + k0 + kcol;
      const unsigned short* gb = wb + (size_t)(n0 + g * 16 + srow) * H + k0 + kcol;
      __builtin_amdgcn_global_load_lds(
          (const __attribute__((address_space(1))) unsigned int*)ga,
          (__attribute__((address_space(3))) unsigned int*)(aLds + g * 16 * 32), 16, 0, 0);
      __builtin_amdgcn_global_load_lds(
          (const __attribute__((address_space(1))) unsigned int*)gb,
          (__attribute__((address_space(3))) unsigned int*)(bLds + g * 16 * 32), 16, 0, 0);
    }
    __syncthreads();

    const int kc = (lane >> 4) * 8;
    const int ar = wr * 64 + (lane & 15);
    const int br = wc * 64 + (lane & 15);
    bf16x8 af[4], bfr[4];
#pragma unroll
    for (int i = 0; i < 4; ++i)
      af[i] = *reinterpret_cast<const bf16x8*>(aLds + (ar + i * 16) * 32 + kc);
#pragma unroll
    for (int jj = 0; jj < 4; ++jj)
      bfr[jj] = *reinterpret_cast<const bf16x8*>(bLds + (br + jj * 16) * 32 + kc);
#pragma unroll
    for (int i = 0; i < 4; ++i)
#pragma unroll
      for (int jj = 0; jj < 4; ++jj)
        acc[i][jj] = __builtin_amdgcn_mfma_f32_16x16x32_bf16(af[i], bfr[jj], acc[i][jj], 0, 0, 0);
    __syncthreads();
  }

  const int cr = (lane >> 4) * 4;
  const int cc = lane & 15;
#pragma unroll
  for (int i = 0; i < 4; ++i)
#pragma unroll
    for (int jj = 0; jj < 4; ++jj)
#pragma unroll
      for (int r = 0; r < 4; ++r)
        out[(size_t)(m0 + wr * 64 + i * 16 + cr + r) * H + (n0 + wc * 64 + jj * 16 + cc)] =
            acc[i][jj][r];
}

// ---------------- scatter v4: 128-lane vec4 streams, 512 threads, 2 waves/token ----------------
__global__ __launch_bounds__(512) void scatter_kernel(
    const float* __restrict__ x, const float* __restrict__ wSortedT,
    const int* __restrict__ elemT, const float4* __restrict__ tokInfo,
    float* __restrict__ out) {
  __shared__ float xrow[4][H];   // 32 KB
  __shared__ float acc[4][H];    // 32 KB
  const int tid  = threadIdx.x;
  const int tk   = tid >> 7;       // token slot 0..3
  const int l    = tid & 127;      // lane within token stream
  const int t0   = blockIdx.x * 4;

  {
    const float4* xsrc = reinterpret_cast<const float4*>(x + (size_t)t0 * H);
    float4* xdst = reinterpret_cast<float4*>(&xrow[0][0]);
    float4* adst = reinterpret_cast<float4*>(&acc[0][0]);
    float4 z; z.x = z.y = z.z = z.w = 0.f;
#pragma unroll
    for (int i = 0; i < 4; ++i) {
      xdst[tid + i * 512] = xsrc[tid + i * 512];
      adst[tid + i * 512] = z;
    }
  }
  __syncthreads();

  const int t = t0 + tk;
  const float4 ti = tokInfo[t];
  const float rw0 = ti.x, rw1 = ti.y;
  const int e0 = __float_as_int(ti.z);
  const int e1 = __float_as_int(ti.w);

  const int4*   ev4 = reinterpret_cast<const int4*>(elemT);
  const float4* w04 = reinterpret_cast<const float4*>(wSortedT + (size_t)e0 * NS);
  const float4* w14 = reinterpret_cast<const float4*>(wSortedT + (size_t)e1 * NS);
  float* xw = &xrow[tk][0];
  float* aw = &acc[tk][0];

  float accv = 0.f;
  int curR = -1;
  int flushed = 0;

  int4   ev = ev4[l];
  float4 a  = w04[l];
  float4 b  = w14[l];

#define PROC1(EV, AV, BV, GV)                                     \
  {                                                               \
    const int r = (EV) >> LOGH;                                   \
    const float ct = (GV) * fmaf(rw0, (AV), rw1 * (BV));          \
    if (r != curR) {                                              \
      if (curR >= 0) {                                            \
        if (flushed) aw[curR] = accv;                             \
        else { atomicAdd(&aw[curR], accv); flushed = 1; }         \
      }                                                           \
      curR = r; accv = ct;                                        \
    } else {                                                      \
      accv += ct;                                                 \
    }                                                             \
  }

#pragma unroll 4
  for (int s = 0; s < 32; ++s) {
    const int sn = (s + 1 <= 31) ? s + 1 : 31;
    int4   evN = ev4[sn * 128 + l];
    float4 aN  = w04[sn * 128 + l];
    float4 bN  = w14[sn * 128 + l];
    const float g0 = xw[ev.x & (H - 1)];
    const float g1 = xw[ev.y & (H - 1)];
    const float g2 = xw[ev.z & (H - 1)];
    const float g3 = xw[ev.w & (H - 1)];
    PROC1(ev.x, a.x, b.x, g0)
    PROC1(ev.y, a.y, b.y, g1)
    PROC1(ev.z, a.z, b.z, g2)
    PROC1(ev.w, a.w, b.w, g3)
    ev = evN; a = aN; b = bN;
  }
  atomicAdd(&aw[curR], accv);  // final flush (row may be shared with next lane)
  __syncthreads();
#undef PROC1

  {
    float4* orow = reinterpret_cast<float4*>(out + (size_t)t * H);
    const float4* arow = reinterpret_cast<const float4*>(aw);
#pragma unroll
    for (int i = 0; i < 4; ++i) {
      int idx = l + i * 128;
      float4 o = orow[idx];
      float4 av = arow[idx];
      o.x += av.x; o.y += av.y; o.z += av.z; o.w += av.w;
      orow[idx] = o;
    }
  }
}

extern "C" void kernel_launch(void* const* d_in, const int* in_sizes, int n_in,
                              void* d_out, int out_size, void* d_ws, size_t ws_size,
                              hipStream_t stream) {
  const float* x          = (const float*)d_in[0];
  const float* gate_w     = (const float*)d_in[1];
  const float* W          = (const float*)d_in[2];
  const float* atoms      = (const float*)d_in[3];
  const float* eaw        = (const float*)d_in[4];
  const float* importance = (const float*)d_in[5];
  const int*   mask_idx   = (const int*)d_in[6];
  float* out = (float*)d_out;

  char* ws = (char*)d_ws;
  size_t off = 0;
  unsigned short* xb = (unsigned short*)(ws + off); off += (size_t)T_TOK * H * 2;  // 16 MB
  unsigned short* wb = (unsigned short*)(ws + off); off += (size_t)H * H * 2;      // 8 MB
  float* weighted    = (float*)(ws + off);          off += (size_t)NEXP * NS * 4;  // 512 KB
  float4* tokInfo    = (float4*)(ws + off);         off += (size_t)T_TOK * 16;     // 64 KB
  int* elemT         = (int*)(ws + off);            off += (size_t)NS * 4;         // 64 KB
  int* sidSorted     = (int*)(ws + off);            off += (size_t)NS * 4;         // 64 KB
  float* wSortedT    = (float*)(ws + off);          off += (size_t)NEXP * NS * 4;  // 512 KB

  prep_kernel<<<T_TOK / 4 + 512, 256, 0, stream>>>(x, gate_w, W, xb, wb, tokInfo);
  weighted_kernel<<<64, 256, 0, stream>>>(eaw, atoms, importance, weighted);
  build_sort_kernel<<<1, 1024, 0, stream>>>(mask_idx, elemT, sidSorted);
  permute_weighted_kernel<<<dim3(NS / 256, NEXP), 256, 0, stream>>>(weighted, sidSorted, wSortedT);
  gemm_kernel<<<512, 256, 0, stream>>>(xb, wb, out);
  scatter_kernel<<<T_TOK / 4, 512, 0, stream>>>(x, wSortedT, elemT, tokInfo, out);
}

// Round 9
// 242.002 us; speedup vs baseline: 2.3441x; 1.1800x over previous
//
#include <hip/hip_runtime.h>
#include <hip/hip_bf16.h>
#include <stdint.h>

#define H       2048
#define LOGH    11
#define T_TOK   4096
#define NEXP    8
#define NATOM   64
#define NS      16384

typedef short bf16x8 __attribute__((ext_vector_type(8)));
typedef float f32x4  __attribute__((ext_vector_type(4)));

__device__ __forceinline__ unsigned short f2bf(float f) {
  union { float f; unsigned u; } c;
  c.f = f;
  c.u += 0x7fff + ((c.u >> 16) & 1);
  return (unsigned short)(c.u >> 16);
}

// ---------------- prep: gate (wave/token) + x->bf16 fused; separate blocks cvt W ----------------
__global__ __launch_bounds__(256) void prep_kernel(
    const float* __restrict__ x, const float* __restrict__ gate_w,
    const float* __restrict__ W, unsigned short* __restrict__ xb,
    unsigned short* __restrict__ wb, float4* __restrict__ tokInfo) {
  const int b = blockIdx.x;
  if (b >= T_TOK / 4) {
    const int wblk = b - T_TOK / 4;
    const float4* src = reinterpret_cast<const float4*>(W);
#pragma unroll
    for (int p = 0; p < 8; ++p) {
      const int i = (wblk + p * 512) * 256 + threadIdx.x;
      float4 v = src[i];
      ushort4 o;
      o.x = f2bf(v.x); o.y = f2bf(v.y); o.z = f2bf(v.z); o.w = f2bf(v.w);
      *reinterpret_cast<ushort4*>(wb + (size_t)i * 4) = o;
    }
    return;
  }
  const int wv = threadIdx.x >> 6;
  const int lane = threadIdx.x & 63;
  const int t = b * 4 + wv;
  const float4* xr = reinterpret_cast<const float4*>(x + (size_t)t * H);
  unsigned short* xbr = xb + (size_t)t * H;

  float accs[NEXP];
#pragma unroll
  for (int e = 0; e < NEXP; ++e) accs[e] = 0.f;
#pragma unroll
  for (int it = 0; it < 8; ++it) {
    const int j4 = it * 64 + lane;
    float4 xv = xr[j4];
    ushort4 o;
    o.x = f2bf(xv.x); o.y = f2bf(xv.y); o.z = f2bf(xv.z); o.w = f2bf(xv.w);
    *reinterpret_cast<ushort4*>(xbr + (size_t)j4 * 4) = o;
#pragma unroll
    for (int e = 0; e < NEXP; ++e) {
      float4 gv = reinterpret_cast<const float4*>(gate_w + (size_t)e * H)[j4];
      accs[e] = fmaf(xv.x, gv.x, accs[e]);
      accs[e] = fmaf(xv.y, gv.y, accs[e]);
      accs[e] = fmaf(xv.z, gv.z, accs[e]);
      accs[e] = fmaf(xv.w, gv.w, accs[e]);
    }
  }
#pragma unroll
  for (int e = 0; e < NEXP; ++e) {
    float v = accs[e];
#pragma unroll
    for (int off = 32; off > 0; off >>= 1) v += __shfl_down(v, off);
    accs[e] = v;
  }
  if (lane == 0) {
    float lg[NEXP];
#pragma unroll
    for (int e = 0; e < NEXP; ++e) lg[e] = fminf(fmaxf(accs[e], -50.f), 50.f);
    int e0 = 0; float w0 = lg[0];
#pragma unroll
    for (int e = 1; e < NEXP; ++e) { if (lg[e] > w0) { w0 = lg[e]; e0 = e; } }
    int e1 = -1; float w1 = -3.4e38f;
#pragma unroll
    for (int e = 0; e < NEXP; ++e) {
      if (e == e0) continue;
      if (lg[e] > w1) { w1 = lg[e]; e1 = e; }
    }
    const float r1 = expf(w1 - w0);  // <= 1
    float4 ti;
    ti.x = 1.f / (1.f + r1);
    ti.y = r1 / (1.f + r1);
    ti.z = __int_as_float(e0);
    ti.w = __int_as_float(e1);
    tokInfo[t] = ti;
  }
}

// ---------------- sorted layout helpers ----------------
// sorted position pos: lane l = pos>>7 owns run [l*128, l*128+128)
// flat index = ((k>>2)<<9) | (l<<2) | (k&3)   where k = pos&127  (vec4-packed per lane)
__device__ __forceinline__ int sortedFlat(int pos) {
  const int l = pos >> 7, k = pos & 127;
  return ((k >> 2) << 9) | (l << 2) | (k & 3);
}

// ---------------- build row-sorted element list + inverse perm + expert softmax probs ----------------
__global__ __launch_bounds__(1024) void build_sort_kernel(
    const int* __restrict__ mask_idx, const float* __restrict__ eaw,
    int* __restrict__ elemT, int* __restrict__ posOfS, float* __restrict__ pbuf) {
  __shared__ int hist[H];
  __shared__ int base[H];
  __shared__ int wsum[16];
  __shared__ int wexc[16];
  const int tid = threadIdx.x;

  // expert softmax probs (independent of the rest; threads 0..7)
  if (tid < NEXP) {
    float v[NATOM];
#pragma unroll
    for (int a = 0; a < NATOM; ++a) v[a] = eaw[tid * NATOM + a];
    float m = v[0];
#pragma unroll
    for (int a = 1; a < NATOM; ++a) m = fmaxf(m, v[a]);
    float ssum = 0.f;
#pragma unroll
    for (int a = 0; a < NATOM; ++a) { v[a] = expf(v[a] - m); ssum += v[a]; }
    const float inv = 1.f / ssum;
#pragma unroll
    for (int a = 0; a < NATOM; ++a) pbuf[tid * NATOM + a] = v[a] * inv;
  }

  hist[tid] = 0;
  hist[tid + 1024] = 0;
  __syncthreads();
  for (int s = tid; s < NS; s += 1024) {
    int r = mask_idx[s] >> LOGH;
    atomicAdd(&hist[r], 1);
  }
  __syncthreads();
  int a = hist[2 * tid], b = hist[2 * tid + 1];
  int ps = a + b;
  const int lane = tid & 63, wid = tid >> 6;
#pragma unroll
  for (int off = 1; off < 64; off <<= 1) {
    int n = __shfl_up(ps, off);
    if (lane >= off) ps += n;
  }
  if (lane == 63) wsum[wid] = ps;
  __syncthreads();
  if (tid == 0) {
    int run = 0;
    for (int w = 0; w < 16; ++w) { wexc[w] = run; run += wsum[w]; }
  }
  __syncthreads();
  int ex = wexc[wid] + ps - (a + b);
  base[2 * tid] = ex;
  base[2 * tid + 1] = ex + a;
  __syncthreads();
  for (int s = tid; s < NS; s += 1024) {
    int m = mask_idx[s];
    int r = m >> LOGH, c = m & (H - 1);
    int pos = atomicAdd(&base[r], 1);
    const int fl = sortedFlat(pos);
    elemT[fl] = (r << LOGH) | c;
    posOfS[s] = fl;
  }
}

// ---------------- weighted v2: s-major, all 8 experts/thread, direct write to sorted layout ----------------
__global__ __launch_bounds__(256) void weighted_kernel(
    const float* __restrict__ pbuf, const float* __restrict__ atoms,
    const float* __restrict__ importance, const int* __restrict__ posOfS,
    float* __restrict__ wSortedT) {
  __shared__ float p[NEXP][NATOM];  // 2 KB
  const int tid = threadIdx.x;
#pragma unroll
  for (int i = tid; i < NEXP * NATOM; i += 256) (&p[0][0])[i] = pbuf[i];
  __syncthreads();

  const int s = blockIdx.x * 256 + tid;
  const float* as = atoms + s;

  float acc[NEXP];
#pragma unroll
  for (int e = 0; e < NEXP; ++e) acc[e] = 0.f;

#pragma unroll
  for (int ab = 0; ab < 8; ++ab) {
    float v[8];
#pragma unroll
    for (int j = 0; j < 8; ++j) v[j] = as[(size_t)(ab * 8 + j) * NS];
#pragma unroll
    for (int j = 0; j < 8; ++j)
#pragma unroll
      for (int e = 0; e < NEXP; ++e) acc[e] = fmaf(p[e][ab * 8 + j], v[j], acc[e]);
  }

  const int fl = posOfS[s];
#pragma unroll
  for (int e = 0; e < NEXP; ++e) {
    const float imp = importance[(size_t)e * NS + s];
    const float sig = 1.f / (1.f + expf(-imp));
    wSortedT[(size_t)e * NS + fl] = acc[e] * sig;
  }
}

// ---------------- bf16 MFMA GEMM with XCD-aware swizzle ----------------
__global__ __launch_bounds__(256) void gemm_kernel(
    const unsigned short* __restrict__ xb, const unsigned short* __restrict__ wb,
    float* __restrict__ out) {
  __shared__ __align__(16) unsigned short aLds[128 * 32];
  __shared__ __align__(16) unsigned short bLds[128 * 32];
  const int tid  = threadIdx.x;
  const int wave = tid >> 6;
  const int lane = tid & 63;
  const int bid = blockIdx.x;
  const int xcd = bid & 7;
  const int j   = bid >> 3;            // 0..63
  const int n_t = (xcd << 1) | (j & 1);
  const int m_t = j >> 1;
  const int m0 = m_t * 128;
  const int n0 = n_t * 128;
  const int wr = wave >> 1;
  const int wc = wave & 1;

  f32x4 acc[4][4];
#pragma unroll
  for (int i = 0; i < 4; ++i)
#pragma unroll
    for (int jj = 0; jj < 4; ++jj)
#pragma unroll
      for (int r = 0; r < 4; ++r) acc[i][jj][r] = 0.f;

  const int srow = lane >> 2;
  const int kcol = (lane & 3) * 8;

  for (int k0 = 0; k0 < H; k0 += 32) {
#pragma unroll
    for (int p = 0; p < 2; ++p) {
      const int g = p * 4 + wave;
      const unsigned short* ga = xb + (size_t)(m0 + g * 16 + srow) * H + k0 + kcol;
      const unsigned short* gb = wb + (size_t)(n0 + g * 16 + srow) * H + k0 + kcol;
      __builtin_amdgcn_global_load_lds(
          (const __attribute__((address_space(1))) unsigned int*)ga,
          (__attribute__((address_space(3))) unsigned int*)(aLds + g * 16 * 32), 16, 0, 0);
      __builtin_amdgcn_global_load_lds(
          (const __attribute__((address_space(1))) unsigned int*)gb,
          (__attribute__((address_space(3))) unsigned int*)(bLds + g * 16 * 32), 16, 0, 0);
    }
    __syncthreads();

    const int kc = (lane >> 4) * 8;
    const int ar = wr * 64 + (lane & 15);
    const int br = wc * 64 + (lane & 15);
    bf16x8 af[4], bfr[4];
#pragma unroll
    for (int i = 0; i < 4; ++i)
      af[i] = *reinterpret_cast<const bf16x8*>(aLds + (ar + i * 16) * 32 + kc);
#pragma unroll
    for (int jj = 0; jj < 4; ++jj)
      bfr[jj] = *reinterpret_cast<const bf16x8*>(bLds + (br + jj * 16) * 32 + kc);
#pragma unroll
    for (int i = 0; i < 4; ++i)
#pragma unroll
      for (int jj = 0; jj < 4; ++jj)
        acc[i][jj] = __builtin_amdgcn_mfma_f32_16x16x32_bf16(af[i], bfr[jj], acc[i][jj], 0, 0, 0);
    __syncthreads();
  }

  const int cr = (lane >> 4) * 4;
  const int cc = lane & 15;
#pragma unroll
  for (int i = 0; i < 4; ++i)
#pragma unroll
    for (int jj = 0; jj < 4; ++jj)
#pragma unroll
      for (int r = 0; r < 4; ++r)
        out[(size_t)(m0 + wr * 64 + i * 16 + cr + r) * H + (n0 + wc * 64 + jj * 16 + cc)] =
            acc[i][jj][r];
}

// ---------------- scatter v4: 128-lane vec4 streams, 512 threads, 2 waves/token ----------------
__global__ __launch_bounds__(512) void scatter_kernel(
    const float* __restrict__ x, const float* __restrict__ wSortedT,
    const int* __restrict__ elemT, const float4* __restrict__ tokInfo,
    float* __restrict__ out) {
  __shared__ float xrow[4][H];   // 32 KB
  __shared__ float acc[4][H];    // 32 KB
  const int tid  = threadIdx.x;
  const int tk   = tid >> 7;       // token slot 0..3
  const int l    = tid & 127;      // lane within token stream
  const int t0   = blockIdx.x * 4;

  {
    const float4* xsrc = reinterpret_cast<const float4*>(x + (size_t)t0 * H);
    float4* xdst = reinterpret_cast<float4*>(&xrow[0][0]);
    float4* adst = reinterpret_cast<float4*>(&acc[0][0]);
    float4 z; z.x = z.y = z.z = z.w = 0.f;
#pragma unroll
    for (int i = 0; i < 4; ++i) {
      xdst[tid + i * 512] = xsrc[tid + i * 512];
      adst[tid + i * 512] = z;
    }
  }
  __syncthreads();

  const int t = t0 + tk;
  const float4 ti = tokInfo[t];
  const float rw0 = ti.x, rw1 = ti.y;
  const int e0 = __float_as_int(ti.z);
  const int e1 = __float_as_int(ti.w);

  const int4*   ev4 = reinterpret_cast<const int4*>(elemT);
  const float4* w04 = reinterpret_cast<const float4*>(wSortedT + (size_t)e0 * NS);
  const float4* w14 = reinterpret_cast<const float4*>(wSortedT + (size_t)e1 * NS);
  float* xw = &xrow[tk][0];
  float* aw = &acc[tk][0];

  float accv = 0.f;
  int curR = -1;
  int flushed = 0;

  int4   ev = ev4[l];
  float4 a  = w04[l];
  float4 b  = w14[l];

#define PROC1(EV, AV, BV, GV)                                     \
  {                                                               \
    const int r = (EV) >> LOGH;                                   \
    const float ct = (GV) * fmaf(rw0, (AV), rw1 * (BV));          \
    if (r != curR) {                                              \
      if (curR >= 0) {                                            \
        if (flushed) aw[curR] = accv;                             \
        else { atomicAdd(&aw[curR], accv); flushed = 1; }         \
      }                                                           \
      curR = r; accv = ct;                                        \
    } else {                                                      \
      accv += ct;                                                 \
    }                                                             \
  }

#pragma unroll 4
  for (int s = 0; s < 32; ++s) {
    const int sn = (s + 1 <= 31) ? s + 1 : 31;
    int4   evN = ev4[sn * 128 + l];
    float4 aN  = w04[sn * 128 + l];
    float4 bN  = w14[sn * 128 + l];
    const float g0 = xw[ev.x & (H - 1)];
    const float g1 = xw[ev.y & (H - 1)];
    const float g2 = xw[ev.z & (H - 1)];
    const float g3 = xw[ev.w & (H - 1)];
    PROC1(ev.x, a.x, b.x, g0)
    PROC1(ev.y, a.y, b.y, g1)
    PROC1(ev.z, a.z, b.z, g2)
    PROC1(ev.w, a.w, b.w, g3)
    ev = evN; a = aN; b = bN;
  }
  atomicAdd(&aw[curR], accv);  // final flush (row may be shared with next lane)
  __syncthreads();
#undef PROC1

  {
    float4* orow = reinterpret_cast<float4*>(out + (size_t)t * H);
    const float4* arow = reinterpret_cast<const float4*>(aw);
#pragma unroll
    for (int i = 0; i < 4; ++i) {
      int idx = l + i * 128;
      float4 o = orow[idx];
      float4 av = arow[idx];
      o.x += av.x; o.y += av.y; o.z += av.z; o.w += av.w;
      orow[idx] = o;
    }
  }
}

extern "C" void kernel_launch(void* const* d_in, const int* in_sizes, int n_in,
                              void* d_out, int out_size, void* d_ws, size_t ws_size,
                              hipStream_t stream) {
  const float* x          = (const float*)d_in[0];
  const float* gate_w     = (const float*)d_in[1];
  const float* W          = (const float*)d_in[2];
  const float* atoms      = (const float*)d_in[3];
  const float* eaw        = (const float*)d_in[4];
  const float* importance = (const float*)d_in[5];
  const int*   mask_idx   = (const int*)d_in[6];
  float* out = (float*)d_out;

  char* ws = (char*)d_ws;
  size_t off = 0;
  unsigned short* xb = (unsigned short*)(ws + off); off += (size_t)T_TOK * H * 2;  // 16 MB
  unsigned short* wb = (unsigned short*)(ws + off); off += (size_t)H * H * 2;      // 8 MB
  float4* tokInfo    = (float4*)(ws + off);         off += (size_t)T_TOK * 16;     // 64 KB
  int* elemT         = (int*)(ws + off);            off += (size_t)NS * 4;         // 64 KB
  int* posOfS        = (int*)(ws + off);            off += (size_t)NS * 4;         // 64 KB
  float* wSortedT    = (float*)(ws + off);          off += (size_t)NEXP * NS * 4;  // 512 KB
  float* pbuf        = (float*)(ws + off);          off += (size_t)NEXP * NATOM * 4;  // 2 KB

  prep_kernel<<<T_TOK / 4 + 512, 256, 0, stream>>>(x, gate_w, W, xb, wb, tokInfo);
  build_sort_kernel<<<1, 1024, 0, stream>>>(mask_idx, eaw, elemT, posOfS, pbuf);
  weighted_kernel<<<NS / 256, 256, 0, stream>>>(pbuf, atoms, importance, posOfS, wSortedT);
  gemm_kernel<<<512, 256, 0, stream>>>(xb, wb, out);
  scatter_kernel<<<T_TOK / 4, 512, 0, stream>>>(x, wSortedT, elemT, tokInfo, out);
}